// Round 1
// baseline (1461.533 us; speedup 1.0000x reference)
//
#include <hip/hip_runtime.h>

// ---- types ----
typedef __bf16 bf16x8 __attribute__((ext_vector_type(8)));
typedef float  f32x4  __attribute__((ext_vector_type(4)));

#define NEG_SLOPE 0.015f

__device__ __forceinline__ unsigned pk_bf16(float x, float y) {
  unsigned a = __builtin_bit_cast(unsigned, x);
  unsigned b = __builtin_bit_cast(unsigned, y);
  a += 0x7fffu + ((a >> 16) & 1u);   // RNE round to bf16
  b += 0x7fffu + ((b >> 16) & 1u);
  return (a >> 16) | (b & 0xffff0000u);
}

__device__ __forceinline__ bf16x8 pack8(const float4 p, const float4 q) {
  union { unsigned u[4]; bf16x8 v; } U;
  U.u[0] = pk_bf16(p.x, p.y);
  U.u[1] = pk_bf16(p.z, p.w);
  U.u[2] = pk_bf16(q.x, q.y);
  U.u[3] = pk_bf16(q.z, q.w);
  return U.v;
}

__device__ __forceinline__ unsigned short f2bf_bits(float x) {
  unsigned a = __builtin_bit_cast(unsigned, x);
  a += 0x7fffu + ((a >> 16) & 1u);
  return (unsigned short)(a >> 16);
}

// ---- K1: W1 [256][128] f32 -> frag-ordered bf16 ----
// layout: elem index = ((kt*8+ct)*64 + lane)*8 + j ; value = W1[kt*32+q*8+j][ct*16+lr]
__global__ void convert_w1(const float* __restrict__ W1,
                           unsigned short* __restrict__ w1f) {
  int idx = blockIdx.x * 256 + threadIdx.x;        // 0..32767
  int j  = idx & 7;
  int l  = (idx >> 3) & 63;
  int f  = idx >> 9;
  int kt = f >> 3, ct = f & 7;
  int q  = l >> 4, lr = l & 15;
  int k  = kt * 32 + q * 8 + j;
  int n  = ct * 16 + lr;
  w1f[idx] = f2bf_bits(W1[k * 128 + n]);
}

// ---- K2: fused GEMM1 (v@W1+b1, LeakyReLU) + segmented sum into acc[G][128] ----
// 128-row tile per block; 4 waves x (2 m-subtiles of 16 rows) x 8 col-tiles.
__global__ __launch_bounds__(256, 2) void fused1(
    const float* __restrict__ v, const int* __restrict__ batch,
    const float* __restrict__ b1, const unsigned short* __restrict__ w1f,
    float* __restrict__ acc) {
  __shared__ unsigned short hs[128][132];   // bf16 h tile, padded pitch (33.8 KB)
  __shared__ int gs[128];                   // graph id per row

  const int tid  = threadIdx.x;
  const int lane = tid & 63, w = tid >> 6;
  const int q    = lane >> 4, lr = lane & 15;
  const int row0 = blockIdx.x * 128;

  if (tid < 128) gs[tid] = batch[row0 + tid];

  const f32x4 zero = {0.f, 0.f, 0.f, 0.f};
  f32x4 c0[8], c1[8];
#pragma unroll
  for (int i = 0; i < 8; ++i) { c0[i] = zero; c1[i] = zero; }

  // A fragments straight from global in MFMA A-layout: m=lane&15, k=q*8+j
  const float* a0p = v + (size_t)(row0 + w * 32 + lr) * 256 + q * 8;
  const float* a1p = a0p + 16 * 256;
  const bf16x8* bp = ((const bf16x8*)w1f) + lane;  // frag-ordered, 1 dwordx4/frag

#pragma unroll
  for (int kt = 0; kt < 8; ++kt) {
    float4 x00 = *(const float4*)(a0p + kt * 32);
    float4 x01 = *(const float4*)(a0p + kt * 32 + 4);
    float4 x10 = *(const float4*)(a1p + kt * 32);
    float4 x11 = *(const float4*)(a1p + kt * 32 + 4);
    bf16x8 a0 = pack8(x00, x01);
    bf16x8 a1 = pack8(x10, x11);
#pragma unroll
    for (int ct = 0; ct < 8; ++ct) {
      bf16x8 b = bp[(kt * 8 + ct) * 64];
      c0[ct] = __builtin_amdgcn_mfma_f32_16x16x32_bf16(a0, b, c0[ct], 0, 0, 0);
      c1[ct] = __builtin_amdgcn_mfma_f32_16x16x32_bf16(a1, b, c1[ct], 0, 0, 0);
    }
  }

  // epilogue: bias + LeakyReLU, store h tile (C/D layout: col=lane&15, row=q*4+r)
#pragma unroll
  for (int ct = 0; ct < 8; ++ct) {
    int col = ct * 16 + lr;
    float bb = b1[col];
#pragma unroll
    for (int r = 0; r < 4; ++r) {
      float y0 = c0[ct][r] + bb;
      float y1 = c1[ct][r] + bb;
      y0 = y0 >= 0.f ? y0 : NEG_SLOPE * y0;
      y1 = y1 >= 0.f ? y1 : NEG_SLOPE * y1;
      hs[w * 32 + q * 4 + r][col]      = f2bf_bits(y0);
      hs[w * 32 + 16 + q * 4 + r][col] = f2bf_bits(y1);
    }
  }
  __syncthreads();

  // segmented (run-length) reduction: thread = (col, half), walk 64 rows
  const int col  = tid & 127;
  const int rbeg = (tid >> 7) * 64;
  float sum = 0.f;
  int gcur  = gs[rbeg];
#pragma unroll 8
  for (int i = 0; i < 64; ++i) {
    int r = rbeg + i;
    int g = gs[r];
    float val = __builtin_bit_cast(float, ((unsigned)hs[r][col]) << 16);
    if (g != gcur) {
      atomicAdd(&acc[(size_t)gcur * 128 + col], sum);
      sum = 0.f; gcur = g;
    }
    sum += val;
  }
  atomicAdd(&acc[(size_t)gcur * 128 + col], sum);
}

// ---- K3: per-graph mean + second Linear (pushed past the mean) ----
__global__ __launch_bounds__(128) void finish2(
    const float* __restrict__ acc, const int* __restrict__ batch, int N,
    const float* __restrict__ W2, const float* __restrict__ b2,
    float* __restrict__ out) {
  const int g = blockIdx.x;
  const int t = threadIdx.x;

  // count = #rows with batch==g (batch sorted ascending)
  int lo = 0, hi = N;
  while (lo < hi) { int mid = (lo + hi) >> 1; if (batch[mid] < g) lo = mid + 1; else hi = mid; }
  int s = lo;
  lo = 0; hi = N;
  while (lo < hi) { int mid = (lo + hi) >> 1; if (batch[mid] <= g) lo = mid + 1; else hi = mid; }
  int cnt = lo - s;

  __shared__ float ms[128];
  float inv = cnt > 0 ? 1.f / (float)cnt : 0.f;
  ms[t] = acc[(size_t)g * 128 + t] * inv;
  __syncthreads();

  float s0 = 0.f, s1 = 0.f, s2 = 0.f, s3 = 0.f;
#pragma unroll
  for (int k = 0; k < 128; k += 4) {
    s0 += ms[k]     * W2[(k)     * 128 + t];
    s1 += ms[k + 1] * W2[(k + 1) * 128 + t];
    s2 += ms[k + 2] * W2[(k + 2) * 128 + t];
    s3 += ms[k + 3] * W2[(k + 3) * 128 + t];
  }
  float r = (s0 + s1) + (s2 + s3) + b2[t];
  out[(size_t)g * 128 + t] = cnt > 0 ? r : 0.f;   // empty graphs -> exact 0
}

extern "C" void kernel_launch(void* const* d_in, const int* in_sizes, int n_in,
                              void* d_out, int out_size, void* d_ws, size_t ws_size,
                              hipStream_t stream) {
  const float* v     = (const float*)d_in[0];
  const int*   batch = (const int*)d_in[1];
  // d_in[2] = num_graphs (scalar) — derived from out_size instead
  const float* W1 = (const float*)d_in[3];
  const float* b1 = (const float*)d_in[4];
  const float* W2 = (const float*)d_in[5];
  const float* b2 = (const float*)d_in[6];
  float* out = (float*)d_out;

  const int N = in_sizes[1];          // 1048576
  const int G = out_size / 128;       // 8192

  float* acc = (float*)d_ws;                                        // G*128 f32 = 4 MB
  unsigned short* w1f = (unsigned short*)((char*)d_ws + (size_t)G * 128 * 4);  // 64 KB

  hipMemsetAsync(acc, 0, (size_t)G * 128 * sizeof(float), stream);
  convert_w1<<<dim3(128), dim3(256), 0, stream>>>(W1, w1f);
  fused1<<<dim3(N / 128), dim3(256), 0, stream>>>(v, batch, b1, w1f, acc);
  finish2<<<dim3(G), dim3(128), 0, stream>>>(acc, batch, N, W2, b2, out);
}